// Round 3
// baseline (187.424 us; speedup 1.0000x reference)
//
#include <hip/hip_runtime.h>

// LSS view transform, segment-list gather formulation.
// out[b,c,cell] = sum_{(pix,d)->cell} img[b,c,pix] * dp[b,d,pix]
// Round-11 changes:
//  - K5 redesigned: k_scan builds a work-list of <=64-entry single-cell
//    segments; one wave per segment. No per-entry key/branch; broadcast via
//    v_readlane (imm lane, SALU) instead of __shfl (ds_bpermute, ~120cyc
//    lgkm-waited per entry). Weight packed with pix in one 32-bit word;
//    1/65535 scale hoisted to flush. Whole-cell segments flush with plain
//    float2 stores -> atomics only for split (>64 entry) cells.
//  - histogram de-sharded (run-compression leaves ~1e5 scattered atomics):
//    k_reduce + k_shardbase dispatches eliminated; k_scan writes cursor copy.
//  - transpose fused into count kernel (independent work, one grid).
//  - 9 -> 6 dispatches.
constexpr int IMG_H = 48, IMG_W = 160;
constexpr int HW    = IMG_H * IMG_W;          // 7680
constexpr int BEV_H = 128, BEV_W = 128;
constexpr int NCELL = BEV_H * BEV_W;          // 16384 per batch
constexpr int C_DIM = 128, D_DIM = 64, B_DIM = 2;
constexpr int NCELL_TOT = B_DIM * NCELL;      // 32768
constexpr int NPIX_TOT  = B_DIM * HW;         // 15360
constexpr int NPTS      = NPIX_TOT * D_DIM;   // 983040
constexpr int SEGLEN    = 64;
constexpr int MAX_SEGS  = NCELL_TOT + NPTS / SEGLEN;   // 48128 (tight bound)
constexpr int CNT_BLOCKS = NPTS / 256;        // 3840
constexpr int TRN_BLOCKS = (HW / 32) * (C_DIM / 32) * B_DIM;  // 1920
constexpr float X_MIN = -51.2f, Y_MIN = -51.2f;
constexpr float RES_X = 102.4f / 128.0f;
constexpr float RES_Y = 102.4f / 128.0f;

typedef _Float16 half2v __attribute__((ext_vector_type(2)));

// ---- ws layout (4-byte words), ~25.4 MB total ----
constexpr size_t WS_IMG_T  = 0;                                      // half[B*HW*C] = 983040 words
constexpr size_t WS_SEGCNT = WS_IMG_T + (size_t)B_DIM * HW * C_DIM / 2;  // int[4]      [memset]
constexpr size_t WS_HIST   = WS_SEGCNT + 4;                          // int[32768]   [memset]
constexpr size_t WS_OUT_T  = WS_HIST + NCELL_TOT;                    // float[32768*128] [memset]
constexpr size_t WS_OFFS   = WS_OUT_T + (size_t)NCELL_TOT * C_DIM;   // int[32768]
constexpr size_t WS_CURS   = WS_OFFS + NCELL_TOT;                    // int[32768]
constexpr size_t WS_EPW    = WS_CURS + NCELL_TOT;                    // uint[NPTS] packed pix|w16
constexpr size_t WS_SEGS   = WS_EPW + NPTS;                          // uint2[MAX_SEGS]
constexpr size_t WS_TOTAL_WORDS = WS_SEGS + (size_t)MAX_SEGS * 2;
// memset range: SEGCNT..end of OUT_T, contiguous
constexpr size_t MEMSET_WORDS = 4 + NCELL_TOT + (size_t)NCELL_TOT * C_DIM;

__device__ inline void make_ray(const float* __restrict__ K, int b, float gx, float gy,
                                float& rx, float& ry, float& rz) {
    const float* Kb = K + b * 9;
    const float a00 = Kb[0], a01 = Kb[1], a02 = Kb[2];
    const float a10 = Kb[3], a11 = Kb[4], a12 = Kb[5];
    const float a20 = Kb[6], a21 = Kb[7], a22 = Kb[8];
    const float det = a00 * (a11 * a22 - a12 * a21)
                    - a01 * (a10 * a22 - a12 * a20)
                    + a02 * (a10 * a21 - a11 * a20);
    const float inv = 1.0f / det;
    const float i00 =  (a11 * a22 - a12 * a21) * inv;
    const float i01 = -(a01 * a22 - a02 * a21) * inv;
    const float i02 =  (a01 * a12 - a02 * a11) * inv;
    const float i10 = -(a10 * a22 - a12 * a20) * inv;
    const float i11 =  (a00 * a22 - a02 * a20) * inv;
    const float i12 = -(a00 * a12 - a02 * a10) * inv;
    const float i20 =  (a10 * a21 - a11 * a20) * inv;
    const float i21 = -(a00 * a21 - a01 * a20) * inv;
    const float i22 =  (a00 * a11 - a01 * a10) * inv;
    rx = i00 * gx + i01 * gy + i02;
    ry = i10 * gx + i11 * gy + i12;
    rz = i20 * gx + i21 * gy + i22;
}

// Returns global cell id (b*NCELL + cell) or -1. tid = ((b*D + d)*HW + pix).
__device__ inline int point_gcell(int tid, const float* __restrict__ dv,
                                  const float* __restrict__ K,
                                  const float* __restrict__ T) {
    const int pix = tid % HW;
    const int bd  = tid / HW;
    const int d   = bd % D_DIM;
    const int b   = bd / D_DIM;
    const int h = pix / IMG_W, w = pix % IMG_W;
    float rx, ry, rz;
    make_ray(K, b, (float)w, (float)h, rx, ry, rz);
    const float* Tb = T + b * 16;
    const float dep = dv[d];                       // wave-uniform
    const float px = dep * rx, py = dep * ry, pz = dep * rz;
    const float x = Tb[0] * px + Tb[1] * py + Tb[2]  * pz + Tb[3];
    const float y = Tb[4] * px + Tb[5] * py + Tb[6]  * pz + Tb[7];
    const float z = Tb[8] * px + Tb[9] * py + Tb[10] * pz + Tb[11];
    const int bx = (int)((x - X_MIN) / RES_X);     // truncate-toward-zero == astype(int32)
    const int by = (int)((y - Y_MIN) / RES_Y);
    const bool valid = (bx >= 0) && (bx < BEV_W) && (by >= 0) && (by < BEV_H) && (z > 0.0f);
    return valid ? (b * NCELL + by * BEV_W + bx) : -1;
}

// Wave-run helpers: lanes are consecutive pixels -> equal-cell runs.
__device__ inline bool wave_runs(int gcell, int lane, int& run_len, int& leader_idx) {
    const int left = __shfl_up(gcell, 1);          // width 64
    const bool is_leader = (lane == 0) || (left != gcell);
    const unsigned long long lmask = __ballot(is_leader);
    const unsigned long long rest = (lane == 63) ? 0ULL : (lmask >> (lane + 1));
    const int f = __ffsll((unsigned long long)rest);   // 1+idx or 0
    run_len = f ? f : (64 - lane);
    const unsigned long long below =
        lmask & ((lane == 63) ? ~0ULL : ((1ULL << (lane + 1)) - 1ULL));
    leader_idx = 63 - __clzll((long long)below);
    return is_leader;
}

// ---- K1: fused {count (blocks 0..3839)} + {transpose/fp16 (blocks 3840..5759)} ----
__global__ __launch_bounds__(256) void k_prep(const float* __restrict__ img,
                                              _Float16* __restrict__ img_t,
                                              const float* __restrict__ dv,
                                              const float* __restrict__ K,
                                              const float* __restrict__ T,
                                              int* __restrict__ hist) {
    __shared__ float tile[32][33];
    if (blockIdx.x < CNT_BLOCKS) {
        const int tid = blockIdx.x * 256 + threadIdx.x;   // < NPTS (exact)
        const int gcell = point_gcell(tid, dv, K, T);
        const int lane = threadIdx.x & 63;
        int run_len, leader_idx;
        const bool lead = wave_runs(gcell, lane, run_len, leader_idx);
        if (lead && gcell >= 0)
            atomicAdd(&hist[gcell], run_len);
    } else {
        const int bi = blockIdx.x - CNT_BLOCKS;
        const int px_t = bi % (HW / 32);
        const int c_t  = (bi / (HW / 32)) % (C_DIM / 32);
        const int b    = bi / ((HW / 32) * (C_DIM / 32));
        const int tx = threadIdx.x & 31, ty = threadIdx.x >> 5;   // (32,8)
        const int pix0 = px_t * 32, c0 = c_t * 32;
        #pragma unroll
        for (int j = 0; j < 32; j += 8)
            tile[ty + j][tx] = img[((size_t)(b * C_DIM + c0 + ty + j)) * HW + pix0 + tx];
        __syncthreads();
        #pragma unroll
        for (int j = 0; j < 32; j += 8)
            img_t[((size_t)(b * HW + pix0 + ty + j)) * C_DIM + c0 + tx] =
                (_Float16)tile[tx][ty + j];
    }
}

// ---- K2: scan + cursor copy + segment build (single block, 1024 thr) ----
__global__ __launch_bounds__(1024) void k_scan(const int* __restrict__ hist,
                                               int* __restrict__ offs,
                                               int* __restrict__ curs,
                                               int* __restrict__ seg_cnt,
                                               uint2* __restrict__ segs) {
    __shared__ int lds[1024];
    const int t = threadIdx.x;
    int h[32];
    int s = 0;
    const int base = t * 32;
    #pragma unroll
    for (int k = 0; k < 32; ++k) { h[k] = hist[base + k]; s += h[k]; }
    lds[t] = s;
    __syncthreads();
    for (int off = 1; off < 1024; off <<= 1) {
        int v = (t >= off) ? lds[t - off] : 0;
        __syncthreads();
        lds[t] += v;
        __syncthreads();
    }
    const int run0 = lds[t] - s;   // exclusive base for this thread's 32 cells
    int run = run0;
    int nseg = 0;
    #pragma unroll
    for (int k = 0; k < 32; ++k) {
        offs[base + k] = run;
        curs[base + k] = run;
        run += h[k];
        nseg += (h[k] + SEGLEN - 1) >> 6;
    }
    int sbase = atomicAdd(seg_cnt, nseg);
    run = run0;
    for (int k = 0; k < 32; ++k) {
        const int cnt = h[k];
        if (cnt > 0) {
            const unsigned whole = (cnt <= SEGLEN) ? 1u : 0u;
            for (int done = 0; done < cnt; done += SEGLEN) {
                const unsigned len = (unsigned)min(SEGLEN, cnt - done);
                segs[sbase++] = make_uint2((unsigned)(run + done),
                                           (unsigned)(base + k) | (len << 15) | (whole << 22));
            }
        }
        run += cnt;
    }
}

// ---- K3: fill packed entries; leader reserves span, lanes write base+rank ----
__global__ __launch_bounds__(256) void k_fill(const float* __restrict__ dp,
                                              const float* __restrict__ dv,
                                              const float* __restrict__ K,
                                              const float* __restrict__ T,
                                              int* __restrict__ curs,
                                              unsigned* __restrict__ epw) {
    const int tid = blockIdx.x * 256 + threadIdx.x;   // < NPTS (exact)
    const int gcell = point_gcell(tid, dv, K, T);
    const int lane = threadIdx.x & 63;
    int run_len, leader_idx;
    const bool lead = wave_runs(gcell, lane, run_len, leader_idx);
    int base = 0;
    if (lead && gcell >= 0)
        base = atomicAdd(&curs[gcell], run_len);
    base = __shfl(base, leader_idx);                  // broadcast my run's base
    if (gcell < 0) return;
    const int slot = base + (lane - leader_idx);      // contiguous, coalesced writes
    const float p = dp[tid];                          // coalesced
    epw[slot] = (unsigned)(tid % HW) | (__float2uint_rn(p * 65535.0f) << 13);
}

// ---- K4: segment gather. One wave per <=64-entry single-cell segment.
// Broadcast via v_readlane imm (SALU, no LDS latency). No per-entry branch.
// Whole-cell segments: plain float2 store; split cells: 2 atomics.
__global__ __launch_bounds__(256) void k_seg_gather(
    const _Float16* __restrict__ img_t,
    const int* __restrict__ seg_cnt,
    const uint2* __restrict__ segs,
    const unsigned* __restrict__ epw,
    float* __restrict__ out_t)
{
    const int nseg = seg_cnt[0];
    const int sidx = blockIdx.x * 4 + (threadIdx.x >> 6);
    if (sidx >= nseg) return;
    const int lane = threadIdx.x & 63;
    const uint2 sg = segs[sidx];
    const int start  = (int)sg.x;
    const int gcell  = (int)(sg.y & 32767u);
    const int len    = (int)((sg.y >> 15) & 127u);
    const bool whole = (sg.y >> 22) & 1u;
    const int bb = gcell >> 14;                       // batch

    unsigned pw = 0;                                  // pad: w=0, pix=0 (harmless)
    if (lane < len) pw = epw[start + lane];

    const int c2 = lane * 2;                          // channels c2, c2+1
    const _Float16* rowbase = img_t + ((size_t)bb * HW) * C_DIM + c2;
    float2 acc = make_float2(0.0f, 0.0f);

#define LOAD16(G, V)                                                             \
    do {                                                                         \
        _Pragma("unroll")                                                        \
        for (int j = 0; j < 16; ++j) {                                           \
            const unsigned sk =                                                  \
                (unsigned)__builtin_amdgcn_readlane((int)pw, (G) * 16 + j);      \
            V[j] = *reinterpret_cast<const half2v*>(                             \
                rowbase + (size_t)(sk & 8191u) * C_DIM);                         \
        }                                                                        \
    } while (0)

#define ACC16(G, V)                                                              \
    do {                                                                         \
        _Pragma("unroll")                                                        \
        for (int j = 0; j < 16; ++j) {                                           \
            const unsigned sk =                                                  \
                (unsigned)__builtin_amdgcn_readlane((int)pw, (G) * 16 + j);      \
            const float w = (float)(sk >> 13);                                   \
            acc.x = fmaf((float)V[j][0], w, acc.x);                              \
            acc.y = fmaf((float)V[j][1], w, acc.y);                              \
        }                                                                        \
    } while (0)

    half2v va[16], vb[16];
    // up to 4 x 16-entry subgroups, 2-deep modulo pipeline, uniform guards
    LOAD16(0, va);
    if (len > 16) LOAD16(1, vb);
    ACC16(0, va);
    if (len > 16) {
        if (len > 32) LOAD16(2, va);
        ACC16(1, vb);
        if (len > 32) {
            if (len > 48) LOAD16(3, vb);
            ACC16(2, va);
            if (len > 48) ACC16(3, vb);
        }
    }
#undef LOAD16
#undef ACC16

    const float scale = 1.0f / 65535.0f;
    const float2 res = make_float2(acc.x * scale, acc.y * scale);
    float* o = &out_t[(size_t)gcell * C_DIM + c2];
    if (whole) {
        *reinterpret_cast<float2*>(o) = res;          // sole owner: plain store
    } else {
        atomicAdd(o, res.x);
        atomicAdd(o + 1, res.y);
    }
}

// ---- K5: untranspose out_t[b][cell][c] -> out[b][c][cell] ----
__global__ __launch_bounds__(256) void k_untranspose(const float* __restrict__ out_t,
                                                     float* __restrict__ out) {
    __shared__ float tile[32][33];
    const int b = blockIdx.z;
    const int tx = threadIdx.x, ty = threadIdx.y;      // block (32, 8)
    const int cell0 = blockIdx.x * 32, c0 = blockIdx.y * 32;
    const float* src = out_t + (size_t)b * NCELL * C_DIM;
    #pragma unroll
    for (int j = 0; j < 32; j += 8)                    // read: c contiguous
        tile[ty + j][tx] = src[((size_t)(cell0 + ty + j)) * C_DIM + c0 + tx];
    __syncthreads();
    #pragma unroll
    for (int j = 0; j < 32; j += 8)                    // write: cell contiguous
        out[((size_t)(b * C_DIM + c0 + ty + j)) * NCELL + cell0 + tx] = tile[tx][ty + j];
}

extern "C" void kernel_launch(void* const* d_in, const int* in_sizes, int n_in,
                              void* d_out, int out_size, void* d_ws, size_t ws_size,
                              hipStream_t stream) {
    const float* img = (const float*)d_in[0];
    const float* dp  = (const float*)d_in[1];
    const float* dv  = (const float*)d_in[2];
    const float* K   = (const float*)d_in[3];
    const float* T   = (const float*)d_in[4];
    float* out = (float*)d_out;

    _Float16* img_t = (_Float16*)d_ws;
    int*   seg_cnt = (int*)d_ws + WS_SEGCNT;
    int*   hist    = (int*)d_ws + WS_HIST;
    float* out_t   = (float*)d_ws + WS_OUT_T;
    int*   offs    = (int*)d_ws + WS_OFFS;
    int*   curs    = (int*)d_ws + WS_CURS;
    unsigned* epw  = (unsigned*)((int*)d_ws + WS_EPW);
    uint2* segs    = (uint2*)((int*)d_ws + WS_SEGS);
    (void)offs; (void)ws_size;

    // zero seg_cnt + hist + out_t in one contiguous memset (~16.9 MB)
    hipMemsetAsync(seg_cnt, 0, MEMSET_WORDS * sizeof(int), stream);

    k_prep<<<CNT_BLOCKS + TRN_BLOCKS, 256, 0, stream>>>(img, img_t, dv, K, T, hist);
    k_scan<<<1, 1024, 0, stream>>>(hist, offs, curs, seg_cnt, segs);
    k_fill<<<NPTS / 256, 256, 0, stream>>>(dp, dv, K, T, curs, epw);
    k_seg_gather<<<MAX_SEGS / 4, 256, 0, stream>>>(img_t, seg_cnt, segs, epw, out_t);
    k_untranspose<<<dim3(NCELL / 32, C_DIM / 32, B_DIM), dim3(32, 8), 0, stream>>>(
        out_t, out);
}

// Round 4
// 147.861 us; speedup vs baseline: 1.2676x; 1.2676x over previous
//
#include <hip/hip_runtime.h>

// LSS view transform, chunked-gather formulation, sharded + wave-run binning,
// cell-major atomic accumulator.
// out[b,c,cell] = sum_{(pix,d)->cell} img[b,c,pix] * dp[b,d,pix]
// Round-12: revert to round-10 structure (154.9us baseline); two isolated deltas:
//  - K5: __shfl (ds_bpermute, lgkm-waited per entry) -> v_readlane with
//    compile-time lane index (SGPR broadcast, no LDS). Flush branch becomes
//    scalar s_cmp; row base becomes SGPR (saddr loads).
//  - transpose fused into count kernel (independent block ranges; sharded
//    hist2 atomics PRESERVED - round-11 de-shard suspected regression).
constexpr int IMG_H = 48, IMG_W = 160;
constexpr int HW    = IMG_H * IMG_W;          // 7680
constexpr int BEV_H = 128, BEV_W = 128;
constexpr int NCELL = BEV_H * BEV_W;          // 16384 per batch
constexpr int C_DIM = 128, D_DIM = 64, B_DIM = 2;
constexpr int NCELL_TOT = B_DIM * NCELL;      // 32768
constexpr int NPIX_TOT  = B_DIM * HW;         // 15360
constexpr int NPTS      = NPIX_TOT * D_DIM;   // 983040
constexpr int MAX_ENTRIES = NPTS;
constexpr int CHUNK = 64;
constexpr int WAVES_PER_BLK = 4;
constexpr int NSHARD = 16;
constexpr int CNT_BLOCKS = NPTS / 256;        // 3840
constexpr int TRN_BLOCKS = (HW / 32) * (C_DIM / 32) * B_DIM;  // 1920
constexpr float X_MIN = -51.2f, Y_MIN = -51.2f;
constexpr float RES_X = 102.4f / 128.0f;
constexpr float RES_Y = 102.4f / 128.0f;

typedef _Float16 half2v __attribute__((ext_vector_type(2)));

// ---- ws layout (4-byte words), ~27.6 MB total ----
// img_t is half: B*HW*C halves = 1,966,080 halves = 983,040 words
constexpr size_t WS_IMG_T = 0;
constexpr size_t WS_IMG_T_WORDS = (size_t)B_DIM * HW * C_DIM / 2;
constexpr size_t WS_HIST2 = WS_IMG_T + WS_IMG_T_WORDS;              // int[NSHARD*32768]
constexpr size_t WS_OUT_T = WS_HIST2 + (size_t)NSHARD * NCELL_TOT;  // float[NCELL_TOT*C] (adjacent -> fused memset)
constexpr size_t WS_HIST  = WS_OUT_T + (size_t)NCELL_TOT * C_DIM;   // int[32768]
constexpr size_t WS_OFFS  = WS_HIST + NCELL_TOT;                    // int[32769] (+3 pad)
constexpr size_t WS_EKEY  = WS_OFFS + NCELL_TOT + 4;                // int[MAX_ENTRIES]
constexpr size_t WS_EW16  = WS_EKEY + MAX_ENTRIES;                  // ushort[MAX_ENTRIES]
constexpr size_t WS_NEED_CM = (WS_EW16 + MAX_ENTRIES / 2) * 4;      // bytes, ~27.6 MB

__device__ inline int point_shard(int tid) {
    return ((tid >> 2) + (tid >> 8)) & (NSHARD - 1);   // deterministic in tid
}

__device__ inline void make_ray(const float* __restrict__ K, int b, float gx, float gy,
                                float& rx, float& ry, float& rz) {
    const float* Kb = K + b * 9;
    const float a00 = Kb[0], a01 = Kb[1], a02 = Kb[2];
    const float a10 = Kb[3], a11 = Kb[4], a12 = Kb[5];
    const float a20 = Kb[6], a21 = Kb[7], a22 = Kb[8];
    const float det = a00 * (a11 * a22 - a12 * a21)
                    - a01 * (a10 * a22 - a12 * a20)
                    + a02 * (a10 * a21 - a11 * a20);
    const float inv = 1.0f / det;
    const float i00 =  (a11 * a22 - a12 * a21) * inv;
    const float i01 = -(a01 * a22 - a02 * a21) * inv;
    const float i02 =  (a01 * a12 - a02 * a11) * inv;
    const float i10 = -(a10 * a22 - a12 * a20) * inv;
    const float i11 =  (a00 * a22 - a02 * a20) * inv;
    const float i12 = -(a00 * a12 - a02 * a10) * inv;
    const float i20 =  (a10 * a21 - a11 * a20) * inv;
    const float i21 = -(a00 * a21 - a01 * a20) * inv;
    const float i22 =  (a00 * a11 - a01 * a10) * inv;
    rx = i00 * gx + i01 * gy + i02;
    ry = i10 * gx + i11 * gy + i12;
    rz = i20 * gx + i21 * gy + i22;
}

// Returns global cell id (b*NCELL + cell) or -1. tid = ((b*D + d)*HW + pix).
__device__ inline int point_gcell(int tid, const float* __restrict__ dv,
                                  const float* __restrict__ K,
                                  const float* __restrict__ T) {
    const int pix = tid % HW;
    const int bd  = tid / HW;
    const int d   = bd % D_DIM;
    const int b   = bd / D_DIM;
    const int h = pix / IMG_W, w = pix % IMG_W;
    float rx, ry, rz;
    make_ray(K, b, (float)w, (float)h, rx, ry, rz);
    const float* Tb = T + b * 16;
    const float dep = dv[d];                       // wave-uniform
    const float px = dep * rx, py = dep * ry, pz = dep * rz;
    const float x = Tb[0] * px + Tb[1] * py + Tb[2]  * pz + Tb[3];
    const float y = Tb[4] * px + Tb[5] * py + Tb[6]  * pz + Tb[7];
    const float z = Tb[8] * px + Tb[9] * py + Tb[10] * pz + Tb[11];
    const int bx = (int)((x - X_MIN) / RES_X);     // truncate-toward-zero == astype(int32)
    const int by = (int)((y - Y_MIN) / RES_Y);
    const bool valid = (bx >= 0) && (bx < BEV_W) && (by >= 0) && (by < BEV_H) && (z > 0.0f);
    return valid ? (b * NCELL + by * BEV_W + bx) : -1;
}

// Wave-run helpers: lanes are consecutive pixels -> equal-cell runs.
__device__ inline bool wave_runs(int gcell, int lane, int& run_len, int& leader_idx) {
    const int left = __shfl_up(gcell, 1);          // width 64
    const bool is_leader = (lane == 0) || (left != gcell);
    const unsigned long long lmask = __ballot(is_leader);
    const unsigned long long rest = (lane == 63) ? 0ULL : (lmask >> (lane + 1));
    const int f = __ffsll((unsigned long long)rest);   // 1+idx or 0
    run_len = f ? f : (64 - lane);
    const unsigned long long below =
        lmask & ((lane == 63) ? ~0ULL : ((1ULL << (lane + 1)) - 1ULL));
    leader_idx = 63 - __clzll((long long)below);
    return is_leader;
}

// ---- K1: fused {sharded count (blocks 0..3839)} + {transpose/fp16 (3840..5759)} ----
__global__ __launch_bounds__(256) void k_prep(const float* __restrict__ img,
                                              _Float16* __restrict__ img_t,
                                              const float* __restrict__ dv,
                                              const float* __restrict__ K,
                                              const float* __restrict__ T,
                                              int* __restrict__ hist2) {
    __shared__ float tile[32][33];
    if (blockIdx.x < CNT_BLOCKS) {
        const int tid = blockIdx.x * 256 + threadIdx.x;   // < NPTS (exact)
        const int gcell = point_gcell(tid, dv, K, T);
        const int lane = threadIdx.x & 63;
        int run_len, leader_idx;
        const bool lead = wave_runs(gcell, lane, run_len, leader_idx);
        if (lead && gcell >= 0)
            atomicAdd(&hist2[(size_t)point_shard(tid) * NCELL_TOT + gcell], run_len);
    } else {
        const int bi = blockIdx.x - CNT_BLOCKS;
        const int px_t = bi % (HW / 32);
        const int c_t  = (bi / (HW / 32)) % (C_DIM / 32);
        const int b    = bi / ((HW / 32) * (C_DIM / 32));
        const int tx = threadIdx.x & 31, ty = threadIdx.x >> 5;   // (32,8)
        const int pix0 = px_t * 32, c0 = c_t * 32;
        #pragma unroll
        for (int j = 0; j < 32; j += 8)
            tile[ty + j][tx] = img[((size_t)(b * C_DIM + c0 + ty + j)) * HW + pix0 + tx];
        __syncthreads();
        #pragma unroll
        for (int j = 0; j < 32; j += 8)
            img_t[((size_t)(b * HW + pix0 + ty + j)) * C_DIM + c0 + tx] =
                (_Float16)tile[tx][ty + j];
    }
}

// ---- K2b: reduce shards -> per-cell totals ----
__global__ __launch_bounds__(256) void k_reduce(const int* __restrict__ hist2,
                                                int* __restrict__ hist) {
    const int cell = blockIdx.x * 256 + threadIdx.x;  // 128 blocks exact
    int s = 0;
    #pragma unroll
    for (int sh = 0; sh < NSHARD; ++sh)
        s += hist2[(size_t)sh * NCELL_TOT + cell];
    hist[cell] = s;
}

// ---- K3: exclusive prefix scan over hist[32768] -> offs[32769] ----
__global__ __launch_bounds__(1024) void k_scan(const int* __restrict__ hist,
                                               int* __restrict__ offs) {
    __shared__ int lds[1024];
    const int t = threadIdx.x;
    int h[32];
    int s = 0;
    const int base = t * 32;
    #pragma unroll
    for (int k = 0; k < 32; ++k) { h[k] = hist[base + k]; s += h[k]; }
    lds[t] = s;
    __syncthreads();
    for (int off = 1; off < 1024; off <<= 1) {
        int v = (t >= off) ? lds[t - off] : 0;
        __syncthreads();
        lds[t] += v;
        __syncthreads();
    }
    int run = lds[t] - s;   // exclusive base for this thread's chunk
    #pragma unroll
    for (int k = 0; k < 32; ++k) {
        offs[base + k] = run;
        run += h[k];
    }
    if (t == 1023) offs[NCELL_TOT] = lds[1023];
}

// ---- K3b: per-cell shard prefix; hist2 becomes cursor bases in place ----
__global__ __launch_bounds__(256) void k_shardbase(int* __restrict__ hist2,
                                                   const int* __restrict__ offs) {
    const int cell = blockIdx.x * 256 + threadIdx.x;  // 128 blocks exact
    int run = offs[cell];
    #pragma unroll
    for (int sh = 0; sh < NSHARD; ++sh) {
        const size_t idx = (size_t)sh * NCELL_TOT + cell;
        const int cnt = hist2[idx];
        hist2[idx] = run;
        run += cnt;
    }
}

// ---- K4: fill entries; leader reserves a span per run, lanes write base+rank ----
__global__ __launch_bounds__(256) void k_fill(const float* __restrict__ dp,
                                              const float* __restrict__ dv,
                                              const float* __restrict__ K,
                                              const float* __restrict__ T,
                                              int* __restrict__ cursor2,   // = hist2 (bases)
                                              int* __restrict__ ekey,
                                              unsigned short* __restrict__ ew16) {
    const int tid = blockIdx.x * 256 + threadIdx.x;   // < NPTS (exact grid)
    const int gcell = point_gcell(tid, dv, K, T);
    const int lane = threadIdx.x & 63;
    int run_len, leader_idx;
    const bool lead = wave_runs(gcell, lane, run_len, leader_idx);
    int base = 0;
    if (lead && gcell >= 0)
        base = atomicAdd(&cursor2[(size_t)point_shard(tid) * NCELL_TOT + gcell], run_len);
    base = __shfl(base, leader_idx);                  // broadcast my run's base
    if (gcell < 0) return;
    const int slot = base + (lane - leader_idx);      // contiguous, coalesced writes
    const float p = dp[tid];                          // tid == ((b*D+d)*HW+pix): coalesced
    ekey[slot] = (gcell << 13) | (tid % HW);
    ew16[slot] = (unsigned short)__float2uint_rn(p * 65535.0f);
}

// ---- K5: chunked segmented reduction. 4 waves/block, wave = one 64-entry
// chunk, thread = 2 channels. Broadcasts via v_readlane (imm lane, SGPR path,
// no ds_bpermute/lgkm chain); flush branch is scalar; row base is SGPR.
// Accumulation order per chunk identical to round 10.
template <bool CELL_MAJOR>
__global__ __launch_bounds__(256) void k_chunk_gather(
    const _Float16* __restrict__ img_t,
    const int* __restrict__ offs,     // offs[NCELL_TOT] = total entry count
    const int* __restrict__ ekey,
    const unsigned short* __restrict__ ew16,
    float* __restrict__ acc_out)
{
    const int total = offs[NCELL_TOT];
    const int wave  = threadIdx.x >> 6;
    const int lane  = threadIdx.x & 63;
    const int base  = (blockIdx.x * WAVES_PER_BLK + wave) * CHUNK;
    if (base >= total) return;

    // per-lane entry fetch (coalesced); pad = dup last key, weight 0
    const int eidx = min(base + lane, total - 1);
    const int   mykey = ekey[eidx];
    const float myw   = (base + lane < total)
                        ? (float)ew16[base + lane] * (1.0f / 65535.0f) : 0.0f;
    const int mywi = __float_as_int(myw);

    const int c2 = lane * 2;                          // channels c2, c2+1
    int prev = __builtin_amdgcn_readlane(mykey, 0) >> 13;
    float2 acc = make_float2(0.0f, 0.0f);

#define LOADG(g, V)                                                              \
    do {                                                                         \
        _Pragma("unroll")                                                        \
        for (int k = 0; k < 8; ++k) {                                            \
            const int key = __builtin_amdgcn_readlane(mykey, (g) * 8 + k);       \
            const int pix = key & 8191;                                          \
            const int bb  = key >> 27;                                           \
            V[k] = *reinterpret_cast<const half2v*>(                             \
                &img_t[((size_t)(bb * HW + pix)) * C_DIM + c2]);                 \
        }                                                                        \
    } while (0)

#define FLUSHP(cell)                                                             \
    do {                                                                         \
        if (CELL_MAJOR) {                                                        \
            float* o = &acc_out[(size_t)(cell) * C_DIM + c2];                    \
            atomicAdd(o, acc.x);                                                 \
            atomicAdd(o + 1, acc.y);                                             \
        } else {                                                                 \
            const int pb = (cell) >> 14, pc = (cell) & (NCELL - 1);              \
            float* o = &acc_out[((size_t)(pb * C_DIM + c2)) * NCELL + pc];       \
            atomicAdd(o, acc.x);                                                 \
            atomicAdd(o + NCELL, acc.y);                                         \
        }                                                                        \
    } while (0)

#define ACCG(g, V)                                                               \
    do {                                                                         \
        _Pragma("unroll")                                                        \
        for (int k = 0; k < 8; ++k) {                                            \
            const int   key = __builtin_amdgcn_readlane(mykey, (g) * 8 + k);     \
            const float wgt =                                                    \
                __int_as_float(__builtin_amdgcn_readlane(mywi, (g) * 8 + k));    \
            const int gcell = key >> 13;                                         \
            if (gcell != prev) {                      /* scalar branch */        \
                FLUSHP(prev);                                                    \
                acc = make_float2(0.0f, 0.0f);                                   \
                prev = gcell;                                                    \
            }                                                                    \
            acc.x = fmaf((float)V[k][0], wgt, acc.x);                            \
            acc.y = fmaf((float)V[k][1], wgt, acc.y);                            \
        }                                                                        \
    } while (0)

    half2v va[8], vb[8];
    // modulo-2 software pipeline over 8 groups of 8 entries (CHUNK=64)
    LOADG(0, va);
    LOADG(1, vb);
    ACCG(0, va);
    LOADG(2, va);
    ACCG(1, vb);
    LOADG(3, vb);
    ACCG(2, va);
    LOADG(4, va);
    ACCG(3, vb);
    LOADG(5, vb);
    ACCG(4, va);
    LOADG(6, va);
    ACCG(5, vb);
    LOADG(7, vb);
    ACCG(6, va);
    ACCG(7, vb);
    FLUSHP(prev);

#undef LOADG
#undef FLUSHP
#undef ACCG
}

// ---- K6: untranspose out_t[b][cell][c] -> out[b][c][cell] ----
__global__ __launch_bounds__(256) void k_untranspose(const float* __restrict__ out_t,
                                                     float* __restrict__ out) {
    __shared__ float tile[32][33];
    const int b = blockIdx.z;
    const int tx = threadIdx.x, ty = threadIdx.y;      // block (32, 8)
    const int cell0 = blockIdx.x * 32, c0 = blockIdx.y * 32;
    const float* src = out_t + (size_t)b * NCELL * C_DIM;
    #pragma unroll
    for (int j = 0; j < 32; j += 8)                    // read: c contiguous
        tile[ty + j][tx] = src[((size_t)(cell0 + ty + j)) * C_DIM + c0 + tx];
    __syncthreads();
    #pragma unroll
    for (int j = 0; j < 32; j += 8)                    // write: cell contiguous
        out[((size_t)(b * C_DIM + c0 + ty + j)) * NCELL + cell0 + tx] = tile[tx][ty + j];
}

extern "C" void kernel_launch(void* const* d_in, const int* in_sizes, int n_in,
                              void* d_out, int out_size, void* d_ws, size_t ws_size,
                              hipStream_t stream) {
    const float* img = (const float*)d_in[0];
    const float* dp  = (const float*)d_in[1];
    const float* dv  = (const float*)d_in[2];
    const float* K   = (const float*)d_in[3];
    const float* T   = (const float*)d_in[4];
    float* out = (float*)d_out;

    float* ws_f   = (float*)d_ws;
    _Float16* img_t = (_Float16*)d_ws;                  // WS_IMG_T == 0
    int*   hist2  = (int*)d_ws + WS_HIST2;
    float* out_t  = ws_f + WS_OUT_T;
    int*   hist   = (int*)d_ws + WS_HIST;
    int*   offs   = (int*)d_ws + WS_OFFS;
    int*   ekey   = (int*)d_ws + WS_EKEY;
    unsigned short* ew16 = (unsigned short*)((int*)d_ws + WS_EW16);

    const bool cell_major = (ws_size >= WS_NEED_CM);

    if (cell_major) {
        // hist2 and out_t are adjacent -> one fused memset (2 MB + 16 MB)
        hipMemsetAsync(hist2, 0,
                       ((size_t)NSHARD * NCELL_TOT + (size_t)NCELL_TOT * C_DIM) * sizeof(int),
                       stream);
    } else {
        hipMemsetAsync(hist2, 0, (size_t)NSHARD * NCELL_TOT * sizeof(int), stream);
        hipMemsetAsync(out, 0, (size_t)out_size * sizeof(float), stream);
    }

    k_prep<<<CNT_BLOCKS + TRN_BLOCKS, 256, 0, stream>>>(img, img_t, dv, K, T, hist2);
    k_reduce<<<NCELL_TOT / 256, 256, 0, stream>>>(hist2, hist);
    k_scan<<<1, 1024, 0, stream>>>(hist, offs);
    k_shardbase<<<NCELL_TOT / 256, 256, 0, stream>>>(hist2, offs);
    k_fill<<<NPTS / 256, 256, 0, stream>>>(dp, dv, K, T, hist2, ekey, ew16);
    constexpr int GATHER_BLOCKS = MAX_ENTRIES / (CHUNK * WAVES_PER_BLK);
    if (cell_major) {
        k_chunk_gather<true><<<GATHER_BLOCKS, 256, 0, stream>>>(
            img_t, offs, ekey, ew16, out_t);
        k_untranspose<<<dim3(NCELL / 32, C_DIM / 32, B_DIM), dim3(32, 8), 0, stream>>>(
            out_t, out);
    } else {
        k_chunk_gather<false><<<GATHER_BLOCKS, 256, 0, stream>>>(
            img_t, offs, ekey, ew16, out);
    }
}